// Round 20
// baseline (599.787 us; speedup 1.0000x reference)
//
#include <hip/hip_runtime.h>
#include <hip/hip_bf16.h>

#define BB 256
#define NN 2048
#define NSTEPS 64
#define DT_C 0.1f
// fp8 scaling: weights x512 (2^9), activations x8 (2^3); acc / 4096 (exact).
#define WSCALE 512.0f
#define ASCALE 8.0f
#define ACC_INV (1.0f / 4096.0f)

#define SLOT (1u << 20)      // per-step A slot: U 512K + PSI 512K
#define PSOFF (1u << 19)

typedef __attribute__((ext_vector_type(4))) float floatx4;
typedef __attribute__((ext_vector_type(4))) float f32x4;

__device__ __forceinline__ floatx4 mfma_fp8(long long a, long long b, floatx4 c) {
  return __builtin_amdgcn_mfma_f32_16x16x32_fp8_fp8(a, b, c, 0, 0, 0);
}

__device__ __forceinline__ unsigned pack4_fp8(float a, float b, float c, float d) {
  int lo = __builtin_amdgcn_cvt_pk_fp8_f32(a, b, 0, false);
  int r  = __builtin_amdgcn_cvt_pk_fp8_f32(c, d, lo, true);
  return (unsigned)r;
}
__device__ __forceinline__ unsigned char fp8byte(float v) {
  return (unsigned char)(__builtin_amdgcn_cvt_pk_fp8_f32(v, 0.f, 0, false) & 0xff);
}

// system-scope: bypass L1/L2, L3-served; cross-XCD coherent, no fences (R13-R19).
__device__ __forceinline__ long long sysload(const long long* p) {
  return __hip_atomic_load(p, __ATOMIC_RELAXED, __HIP_MEMORY_SCOPE_SYSTEM);
}
__device__ __forceinline__ unsigned sysloadu(const unsigned* p) {
  return __hip_atomic_load(p, __ATOMIC_RELAXED, __HIP_MEMORY_SCOPE_SYSTEM);
}
__device__ __forceinline__ void sysstore(unsigned* p, unsigned v) {
  __hip_atomic_store(p, v, __ATOMIC_RELAXED, __HIP_MEMORY_SCOPE_SYSTEM);
}
// CACHED path: normal load; per-step-unique slots + one entry fence (R17-proven).
template <bool C>
__device__ __forceinline__ long long aload(const long long* p) {
  if constexpr (C) return *p;
  else return sysload(p);
}

// ---------------- fragment-major fp8 layouts (verified R11-R19) ----------------
// frag(rf=row>>4, kc=k>>5), frag idx = rf*64+kc, 512 BYTES per frag;
// in-frag byte = lane*8 + (k&7), lane = (row&15) | (((k>>3)&3)<<4).

__global__ __launch_bounds__(256) void convert_kernel(
    const float* __restrict__ Ww, unsigned char* __restrict__ Wf,
    const float* __restrict__ Tw, unsigned char* __restrict__ Tf, int half) {
  int bid = blockIdx.x;
  const float* src = Ww;
  unsigned char* dst = Wf;
  if (bid >= half) { bid -= half; src = Tw; dst = Tf; }
  const int g = bid * 256 + threadIdx.x;
  const int frag = g >> 6, l = g & 63;
  const int j = (frag >> 6) * 16 + (l & 15);
  const int k = (frag & 63) * 32 + (l >> 4) * 8;
  const float* s = src + (size_t)j * NN + k;
  unsigned lo = pack4_fp8(s[0] * WSCALE, s[1] * WSCALE, s[2] * WSCALE, s[3] * WSCALE);
  unsigned hi = pack4_fp8(s[4] * WSCALE, s[5] * WSCALE, s[6] * WSCALE, s[7] * WSCALE);
  ((unsigned long long*)dst)[g] = ((unsigned long long)hi << 32) | lo;
}

__global__ __launch_bounds__(256) void init_kernel(
    const float* __restrict__ x0, unsigned char* __restrict__ Ab) {
  const int i = blockIdx.x * 256 + threadIdx.x;
  const int b = i >> 11, j = i & (NN - 1);
  const float r = fmaxf(x0[i], 0.f);
  const int dl = (b & 15) | (((j >> 3) & 3) << 4);
  const size_t fo = ((size_t)((b >> 4) * 64 + (j >> 5))) * 512 + dl * 8 + (j & 7);
  Ab[fo] = fp8byte(ASCALE * r * r);          // U slot 0
  Ab[PSOFF + fo] = fp8byte(ASCALE * r);      // PSI slot 0
}

#define LOADA(S, kc) \
  S##a0 = aload<CACHED>(aP0 + (size_t)(kc) * 64); \
  S##a1 = aload<CACHED>(aP1 + (size_t)(kc) * 64);
#define LOADB(S, kc) \
  S##b0 = bP0[(size_t)(kc) * 64]; \
  S##b1 = bP1[(size_t)(kc) * 64]; \
  S##b2 = bP2[(size_t)(kc) * 64]; \
  S##b3 = bP3[(size_t)(kc) * 64];
#define DOMFMA(S) \
  acc00 = mfma_fp8(S##a0, S##b0, acc00); acc01 = mfma_fp8(S##a0, S##b1, acc01); \
  acc02 = mfma_fp8(S##a0, S##b2, acc02); acc03 = mfma_fp8(S##a0, S##b3, acc03); \
  acc10 = mfma_fp8(S##a1, S##b0, acc10); acc11 = mfma_fp8(S##a1, S##b1, acc11); \
  acc12 = mfma_fp8(S##a1, S##b2, acc12); acc13 = mfma_fp8(S##a1, S##b3, acc13);

// Persistent cooperative kernel, all 64 steps. R19 structure (32x64 tile,
// 8 rowt x 32 colt; 8 waves = 2 GEMM x 4 K-quarter; 2A x 4B per wave;
// cross-step B prefetch; deferred xs store).
// R20: NO global barrier. Dataflow sync: producer block sets
// flag[rowt][colt]=t+1 once its U/PS sysstores are L3-visible; consumer wave h
// (needs K cols [512h,512h+512) = producers colt' in [8h,8h+8) of its rowt)
// polls just those 8 flags. Waves unblock independently -> cross-step pipelining.
// Per-step-unique A slots guarantee no WAR and no stale-L2 lines (R17 logic).
template <bool CACHED>
__global__ __launch_bounds__(512) void fused_kernel(
    const unsigned char* __restrict__ Wf, const unsigned char* __restrict__ Tf,
    const float* __restrict__ Wb, const float* __restrict__ Tb,
    const float* __restrict__ wp2s, const float* __restrict__ ws2p,
    const float* __restrict__ fri, const float* __restrict__ x0,
    unsigned char* __restrict__ Ab,
    float* __restrict__ out, unsigned* __restrict__ bar) {
  __shared__ float eb[8][32][68];   // per-wave 32x64 f32 partials, padded

  if constexpr (CACHED)   // one-time invalidate (L1+L2, no dirty ws lines)
    __builtin_amdgcn_fence(__ATOMIC_ACQUIRE, "agent");

  const int tid = threadIdx.x;
  const int lane = tid & 63, wv = tid >> 6;
  const int lane15 = lane & 15, kq = lane >> 4;
  const int g = wv >> 2, h = wv & 3;

  const int x = blockIdx.x & 7, ii = blockIdx.x >> 3;
  const int colt = x * 4 + (ii & 3), rowt = ii >> 2;   // 32 colt, 8 rowt
  const int b0 = rowt * 32, j0 = colt * 64;

  // ---- per-thread epilogue constants and register state (held 64 steps) ----
  const int erow = tid >> 4;
  const int c4 = (tid & 15) << 2;
  const int ej = j0 + c4;
  const size_t eidx = (size_t)(b0 + erow) * NN + ej;
  const f32x4 Wb4 = *(const f32x4*)(Wb + ej);
  const f32x4 Tb4 = *(const f32x4*)(Tb + ej);
  const f32x4 wp4 = *(const f32x4*)(wp2s + ej);
  const f32x4 ws4 = *(const f32x4*)(ws2p + ej);
  const f32x4 fr4 = *(const f32x4*)(fri + eidx);
  f32x4 xcur = *(const f32x4*)(x0 + eidx);
  f32x4 scur = xcur, pcur = xcur;     // s0 = p0 = x0

  const int bb = b0 + erow;
  const int dl = (bb & 15) | (((ej >> 3) & 3) << 4);
  const size_t fob = ((size_t)((bb >> 4) * 64 + (ej >> 5))) * 512 + dl * 8 + (ej & 7);

  // ---- GEMM stream geometry ----
  const int rf0 = rowt * 2;
  const int cf0 = colt * 4;
  const int kcb = h * 16;
  const unsigned char* Bfm = g == 0 ? Wf : Tf;
  const long long* bP0 = (const long long*)Bfm + ((size_t)(cf0 + 0) * 64 + kcb) * 64 + lane;
  const long long* bP1 = (const long long*)Bfm + ((size_t)(cf0 + 1) * 64 + kcb) * 64 + lane;
  const long long* bP2 = (const long long*)Bfm + ((size_t)(cf0 + 2) * 64 + kcb) * 64 + lane;
  const long long* bP3 = (const long long*)Bfm + ((size_t)(cf0 + 3) * 64 + kcb) * 64 + lane;
  const size_t aOff0 = ((size_t)(rf0 + 0) * 64 + kcb) * 64 + lane;
  const size_t aOff1 = ((size_t)(rf0 + 1) * 64 + kcb) * 64 + lane;

  // producer flags this wave depends on: colt' in [8h, 8h+8) of same rowt
  const unsigned* myflags = bar + rowt * 32 + 8 * h + (lane & 7);

  float* xs = out + (size_t)BB * NN;

  // pipeline registers: live ACROSS steps (B prefetched over the sync)
  long long Aa0, Aa1, Ab0, Ab1, Ab2, Ab3;
  long long Ba0, Ba1, Bb0, Bb1, Bb2, Bb3;
  long long Ca0, Ca1, Cb0, Cb1, Cb2, Cb3;
  long long Da0, Da1, Db0, Db1, Db2, Db3;
  LOADB(A, 0) LOADB(B, 1) LOADB(C, 2) LOADB(D, 3)   // initial B fill

  for (int t = 0; t < NSTEPS; ++t) {
    const unsigned rs  = CACHED ? (unsigned)t : (unsigned)(t & 1);
    const unsigned wsl = CACHED ? (unsigned)(t + 1) : (unsigned)((t + 1) & 1);
    const unsigned char* Ar = Ab + (size_t)rs * SLOT + (g == 0 ? 0u : PSOFF);
    unsigned char* Uw  = Ab + (size_t)wsl * SLOT;
    unsigned char* PSw = Uw + PSOFF;
    const long long* aP0 = (const long long*)Ar + aOff0;
    const long long* aP1 = (const long long*)Ar + aOff1;

    if (CACHED && t > 0) {
      // ---- dataflow wait: this wave's 8 producers must have finished step t-1
      for (;;) {
        int ok = 1;
        if ((lane & 63) < 8) ok = (sysloadu(myflags) >= (unsigned)t) ? 1 : 0;
        if (__all(ok)) break;
        __builtin_amdgcn_s_sleep(1);
      }
      asm volatile("" ::: "memory");           // pin A loads after the poll
      __builtin_amdgcn_sched_barrier(0);
    }

    LOADA(A, 0) LOADA(B, 1) LOADA(C, 2) LOADA(D, 3)   // A half of the fill

    floatx4 acc00 = {0.f,0.f,0.f,0.f}, acc01 = {0.f,0.f,0.f,0.f};
    floatx4 acc02 = {0.f,0.f,0.f,0.f}, acc03 = {0.f,0.f,0.f,0.f};
    floatx4 acc10 = {0.f,0.f,0.f,0.f}, acc11 = {0.f,0.f,0.f,0.f};
    floatx4 acc12 = {0.f,0.f,0.f,0.f}, acc13 = {0.f,0.f,0.f,0.f};

    for (int kc = 0; kc < 12; kc += 4) {   // compute 0..11, load 4..15
      DOMFMA(A) LOADA(A, kc + 4) LOADB(A, kc + 4)
      DOMFMA(B) LOADA(B, kc + 5) LOADB(B, kc + 5)
      DOMFMA(C) LOADA(C, kc + 6) LOADB(C, kc + 6)
      DOMFMA(D) LOADA(D, kc + 7) LOADB(D, kc + 7)
    }
    // tail: consume kc 12..15 while prefetching NEXT STEP's B (kc 0..3)
    DOMFMA(A) LOADB(A, 0)
    DOMFMA(B) LOADB(B, 1)
    DOMFMA(C) LOADB(C, 2)
    DOMFMA(D) LOADB(D, 3)

    // publish partials: eb[wv][row 0..31][col 0..63]
#pragma unroll
    for (int r = 0; r < 4; ++r) {
      eb[wv][kq * 4 + r][lane15]      = acc00[r];
      eb[wv][kq * 4 + r][16 + lane15] = acc01[r];
      eb[wv][kq * 4 + r][32 + lane15] = acc02[r];
      eb[wv][kq * 4 + r][48 + lane15] = acc03[r];
      eb[wv][16 + kq * 4 + r][lane15]      = acc10[r];
      eb[wv][16 + kq * 4 + r][16 + lane15] = acc11[r];
      eb[wv][16 + kq * 4 + r][32 + lane15] = acc12[r];
      eb[wv][16 + kq * 4 + r][48 + lane15] = acc13[r];
    }
    __syncthreads();

    // ---- epilogue on register state ----
    f32x4 m1, m2;
    {
      const f32x4 p0 = *(const f32x4*)&eb[0][erow][c4];
      const f32x4 p1 = *(const f32x4*)&eb[1][erow][c4];
      const f32x4 p2 = *(const f32x4*)&eb[2][erow][c4];
      const f32x4 p3 = *(const f32x4*)&eb[3][erow][c4];
      const f32x4 q0 = *(const f32x4*)&eb[4][erow][c4];
      const f32x4 q1 = *(const f32x4*)&eb[5][erow][c4];
      const f32x4 q2 = *(const f32x4*)&eb[6][erow][c4];
      const f32x4 q3 = *(const f32x4*)&eb[7][erow][c4];
      m1 = ((p0 + p1) + (p2 + p3)) * ACC_INV;
      m2 = ((q0 + q1) + (q2 + q3)) * ACC_INV;
    }
    float uf[4], pf[4];
#pragma unroll
    for (int e = 0; e < 4; ++e) {
      const float xv = xcur[e], s = scur[e], p = pcur[e];
      const float phi = fmaxf(xv, 0.f), gg = fmaxf(s, 0.f), psi = fmaxf(p, 0.f);
      const float xn = xv + DT_C * (-xv + m1[e] + Wb4[e]) * fr4[e];
      const float sn = p + DT_C * (-s + wp4[e] * psi + phi);   // base is p (as in source)
      const float pn = p + DT_C * (-p + m2[e] + Tb4[e] + ws4[e] * gg);
      xcur[e] = xn; scur[e] = sn; pcur[e] = pn;
      uf[e] = ASCALE * fmaxf(xn, 0.f) * fmaxf(sn, 0.f);
      pf[e] = ASCALE * fmaxf(pn, 0.f);
    }
    if (t == NSTEPS - 1) {
      __builtin_nontemporal_store(xcur, (f32x4*)(xs + (size_t)t * BB * NN + eidx));
      __builtin_nontemporal_store(xcur, (f32x4*)(out + eidx));
    } else {
      sysstore((unsigned*)(Uw + fob), pack4_fp8(uf[0], uf[1], uf[2], uf[3]));
      sysstore((unsigned*)(PSw + fob), pack4_fp8(pf[0], pf[1], pf[2], pf[3]));
      asm volatile("s_waitcnt vmcnt(0)" ::: "memory");  // U,PS visible at L3
      __syncthreads();                                  // all waves' stores done;
                                                        // also closes eb-reuse window
      if constexpr (CACHED) {
        if (tid == 0)
          sysstore(bar + rowt * 32 + colt, (unsigned)(t + 1));  // publish step done
        __builtin_nontemporal_store(xcur,               // HBM write rides the poll
            (f32x4*)(xs + (size_t)t * BB * NN + eidx));
      } else {
        // fallback: R17-style hierarchical global barrier
        __builtin_nontemporal_store(xcur,
            (f32x4*)(xs + (size_t)t * BB * NN + eidx));
        if (tid == 0) {
          unsigned* root = bar + 256;
          unsigned* leaf = root + 32 * (1 + x);
          const unsigned v = __hip_atomic_fetch_add(leaf, 1u, __ATOMIC_RELAXED,
                                                    __HIP_MEMORY_SCOPE_AGENT);
          if (v + 1 == 32u * (unsigned)(t + 1))
            __hip_atomic_fetch_add(root, 1u, __ATOMIC_RELAXED,
                                   __HIP_MEMORY_SCOPE_AGENT);
          while (__hip_atomic_load(root, __ATOMIC_RELAXED,
                                   __HIP_MEMORY_SCOPE_AGENT) < 8u * (unsigned)(t + 1))
            __builtin_amdgcn_s_sleep(1);
        }
        __syncthreads();
      }
    }
  }
}

extern "C" void kernel_launch(void* const* d_in, const int* in_sizes, int n_in,
                              void* d_out, int out_size, void* d_ws, size_t ws_size,
                              hipStream_t stream) {
  const float* x0   = (const float*)d_in[0];
  const float* fri  = (const float*)d_in[1];
  const float* Ww   = (const float*)d_in[2];
  const float* Wb   = (const float*)d_in[3];
  const float* Tw   = (const float*)d_in[4];
  const float* Tb   = (const float*)d_in[5];
  const float* wp2s = (const float*)d_in[6];
  const float* ws2p = (const float*)d_in[7];
  float* out = (float*)d_out;

  const size_t BN = (size_t)BB * NN;
  const size_t NW = (size_t)NN * NN;

  const size_t needCached = 4096 + 64 * (size_t)SLOT + 2 * NW;  // ~75.5 MB
  const bool cached = ws_size >= needCached;
  const size_t nslots = cached ? 64 : 2;

  unsigned* bar = (unsigned*)d_ws;                       // 4 KB (flags + fallback)
  unsigned char* Abuf = (unsigned char*)d_ws + 4096;     // nslots x 1 MB
  unsigned char* Wf = Abuf + nslots * (size_t)SLOT;
  unsigned char* Tf = Wf + NW;

  hipMemsetAsync(bar, 0, 4096, stream);
  const int chalf = (int)(NW / 2048);
  convert_kernel<<<2 * chalf, 256, 0, stream>>>(Ww, Wf, Tw, Tf, chalf);
  init_kernel<<<(int)(BN / 256), 256, 0, stream>>>(x0, Abuf);

  void* kargs[] = {
    (void*)&Wf, (void*)&Tf, (void*)&Wb, (void*)&Tb, (void*)&wp2s, (void*)&ws2p,
    (void*)&fri, (void*)&x0, (void*)&Abuf, (void*)&out, (void*)&bar
  };
  if (cached) {
    hipLaunchCooperativeKernel((const void*)fused_kernel<true>, dim3(256),
                               dim3(512), kargs, 0, stream);
  } else {
    hipLaunchCooperativeKernel((const void*)fused_kernel<false>, dim3(256),
                               dim3(512), kargs, 0, stream);
  }
}

// Round 21
// 458.342 us; speedup vs baseline: 1.3086x; 1.3086x over previous
//
#include <hip/hip_runtime.h>
#include <hip/hip_bf16.h>

#define BB 256
#define NN 2048
#define NSTEPS 64
#define DT_C 0.1f
// fp8 scaling: weights x512 (2^9), activations x8 (2^3); acc / 4096 (exact).
#define WSCALE 512.0f
#define ASCALE 8.0f
#define ACC_INV (1.0f / 4096.0f)

#define SLOT (1u << 20)      // per-step A slot: U 512K + PSI 512K
#define PSOFF (1u << 19)

typedef __attribute__((ext_vector_type(4))) float floatx4;
typedef __attribute__((ext_vector_type(4))) float f32x4;

__device__ __forceinline__ floatx4 mfma_fp8(long long a, long long b, floatx4 c) {
  return __builtin_amdgcn_mfma_f32_16x16x32_fp8_fp8(a, b, c, 0, 0, 0);
}

__device__ __forceinline__ unsigned pack4_fp8(float a, float b, float c, float d) {
  int lo = __builtin_amdgcn_cvt_pk_fp8_f32(a, b, 0, false);
  int r  = __builtin_amdgcn_cvt_pk_fp8_f32(c, d, lo, true);
  return (unsigned)r;
}
__device__ __forceinline__ unsigned char fp8byte(float v) {
  return (unsigned char)(__builtin_amdgcn_cvt_pk_fp8_f32(v, 0.f, 0, false) & 0xff);
}

// system-scope: bypass L1/L2, L3-served; cross-XCD coherent, no fences (R13-R19).
__device__ __forceinline__ long long sysload(const long long* p) {
  return __hip_atomic_load(p, __ATOMIC_RELAXED, __HIP_MEMORY_SCOPE_SYSTEM);
}
__device__ __forceinline__ void sysstore(unsigned* p, unsigned v) {
  __hip_atomic_store(p, v, __ATOMIC_RELAXED, __HIP_MEMORY_SCOPE_SYSTEM);
}
// CACHED path: normal load; per-step-unique slots + one entry fence (R17-proven).
template <bool C>
__device__ __forceinline__ long long aload(const long long* p) {
  if constexpr (C) return *p;
  else return sysload(p);
}

// ---------------- fragment-major fp8 layouts (verified R11-R19) ----------------
// frag(rf=row>>4, kc=k>>5), frag idx = rf*64+kc, 512 BYTES per frag;
// in-frag byte = lane*8 + (k&7), lane = (row&15) | (((k>>3)&3)<<4).

__global__ __launch_bounds__(256) void convert_kernel(
    const float* __restrict__ Ww, unsigned char* __restrict__ Wf,
    const float* __restrict__ Tw, unsigned char* __restrict__ Tf, int half) {
  int bid = blockIdx.x;
  const float* src = Ww;
  unsigned char* dst = Wf;
  if (bid >= half) { bid -= half; src = Tw; dst = Tf; }
  const int g = bid * 256 + threadIdx.x;
  const int frag = g >> 6, l = g & 63;
  const int j = (frag >> 6) * 16 + (l & 15);
  const int k = (frag & 63) * 32 + (l >> 4) * 8;
  const float* s = src + (size_t)j * NN + k;
  unsigned lo = pack4_fp8(s[0] * WSCALE, s[1] * WSCALE, s[2] * WSCALE, s[3] * WSCALE);
  unsigned hi = pack4_fp8(s[4] * WSCALE, s[5] * WSCALE, s[6] * WSCALE, s[7] * WSCALE);
  ((unsigned long long*)dst)[g] = ((unsigned long long)hi << 32) | lo;
}

__global__ __launch_bounds__(256) void init_kernel(
    const float* __restrict__ x0, unsigned char* __restrict__ Ab) {
  const int i = blockIdx.x * 256 + threadIdx.x;
  const int b = i >> 11, j = i & (NN - 1);
  const float r = fmaxf(x0[i], 0.f);
  const int dl = (b & 15) | (((j >> 3) & 3) << 4);
  const size_t fo = ((size_t)((b >> 4) * 64 + (j >> 5))) * 512 + dl * 8 + (j & 7);
  Ab[fo] = fp8byte(ASCALE * r * r);          // U slot 0
  Ab[PSOFF + fo] = fp8byte(ASCALE * r);      // PSI slot 0
}

#define LOADA(S, kc) \
  S##a0 = aload<CACHED>(aP0 + (size_t)(kc) * 64); \
  S##a1 = aload<CACHED>(aP1 + (size_t)(kc) * 64);
#define LOADB(S, kc) \
  S##b0 = bP0[(size_t)(kc) * 64]; \
  S##b1 = bP1[(size_t)(kc) * 64]; \
  S##b2 = bP2[(size_t)(kc) * 64]; \
  S##b3 = bP3[(size_t)(kc) * 64];
#define DOMFMA(S) \
  acc00 = mfma_fp8(S##a0, S##b0, acc00); acc01 = mfma_fp8(S##a0, S##b1, acc01); \
  acc02 = mfma_fp8(S##a0, S##b2, acc02); acc03 = mfma_fp8(S##a0, S##b3, acc03); \
  acc10 = mfma_fp8(S##a1, S##b0, acc10); acc11 = mfma_fp8(S##a1, S##b1, acc11); \
  acc12 = mfma_fp8(S##a1, S##b2, acc12); acc13 = mfma_fp8(S##a1, S##b3, acc13);

// Persistent cooperative kernel, all 64 steps. R17 structure (32x64 tile,
// 8 rowt x 32 colt; 8 waves = 2 GEMM x 4 K-quarter; per wave 2A x 4B;
// hierarchical RMW barrier). R19 additions (best config, 459 us):
//  - xs nt-store deferred past vmcnt(0) (rides the barrier spin)
//  - next-step B prefetch interleaved with tail MFMAs (B streams are
//    step-invariant; regs live across the barrier -> post-barrier refill
//    only needs the A half of the pipeline)
template <bool CACHED>
__global__ __launch_bounds__(512) void fused_kernel(
    const unsigned char* __restrict__ Wf, const unsigned char* __restrict__ Tf,
    const float* __restrict__ Wb, const float* __restrict__ Tb,
    const float* __restrict__ wp2s, const float* __restrict__ ws2p,
    const float* __restrict__ fri, const float* __restrict__ x0,
    unsigned char* __restrict__ Ab,
    float* __restrict__ out, unsigned* __restrict__ bar) {
  __shared__ float eb[8][32][68];   // per-wave 32x64 f32 partials, padded

  if constexpr (CACHED)   // one-time invalidate (L1+L2, no dirty ws lines)
    __builtin_amdgcn_fence(__ATOMIC_ACQUIRE, "agent");

  const int tid = threadIdx.x;
  const int lane = tid & 63, wv = tid >> 6;
  const int lane15 = lane & 15, kq = lane >> 4;
  const int g = wv >> 2, h = wv & 3;

  const int x = blockIdx.x & 7, ii = blockIdx.x >> 3;
  const int colt = x * 4 + (ii & 3), rowt = ii >> 2;   // 32 colt, 8 rowt
  const int b0 = rowt * 32, j0 = colt * 64;

  // ---- per-thread epilogue constants and register state (held 64 steps) ----
  const int erow = tid >> 4;
  const int c4 = (tid & 15) << 2;
  const int ej = j0 + c4;
  const size_t eidx = (size_t)(b0 + erow) * NN + ej;
  const f32x4 Wb4 = *(const f32x4*)(Wb + ej);
  const f32x4 Tb4 = *(const f32x4*)(Tb + ej);
  const f32x4 wp4 = *(const f32x4*)(wp2s + ej);
  const f32x4 ws4 = *(const f32x4*)(ws2p + ej);
  const f32x4 fr4 = *(const f32x4*)(fri + eidx);
  f32x4 xcur = *(const f32x4*)(x0 + eidx);
  f32x4 scur = xcur, pcur = xcur;     // s0 = p0 = x0

  const int bb = b0 + erow;
  const int dl = (bb & 15) | (((ej >> 3) & 3) << 4);
  const size_t fob = ((size_t)((bb >> 4) * 64 + (ej >> 5))) * 512 + dl * 8 + (ej & 7);

  // ---- GEMM stream geometry ----
  const int rf0 = rowt * 2;
  const int cf0 = colt * 4;
  const int kcb = h * 16;
  const unsigned char* Bfm = g == 0 ? Wf : Tf;
  const long long* bP0 = (const long long*)Bfm + ((size_t)(cf0 + 0) * 64 + kcb) * 64 + lane;
  const long long* bP1 = (const long long*)Bfm + ((size_t)(cf0 + 1) * 64 + kcb) * 64 + lane;
  const long long* bP2 = (const long long*)Bfm + ((size_t)(cf0 + 2) * 64 + kcb) * 64 + lane;
  const long long* bP3 = (const long long*)Bfm + ((size_t)(cf0 + 3) * 64 + kcb) * 64 + lane;
  const size_t aOff0 = ((size_t)(rf0 + 0) * 64 + kcb) * 64 + lane;
  const size_t aOff1 = ((size_t)(rf0 + 1) * 64 + kcb) * 64 + lane;

  float* xs = out + (size_t)BB * NN;

  // pipeline registers: live ACROSS steps (B prefetched over the barrier)
  long long Aa0, Aa1, Ab0, Ab1, Ab2, Ab3;
  long long Ba0, Ba1, Bb0, Bb1, Bb2, Bb3;
  long long Ca0, Ca1, Cb0, Cb1, Cb2, Cb3;
  long long Da0, Da1, Db0, Db1, Db2, Db3;
  LOADB(A, 0) LOADB(B, 1) LOADB(C, 2) LOADB(D, 3)   // initial B fill

  for (int t = 0; t < NSTEPS; ++t) {
    const unsigned rs  = CACHED ? (unsigned)t : (unsigned)(t & 1);
    const unsigned wsl = CACHED ? (unsigned)(t + 1) : (unsigned)((t + 1) & 1);
    const unsigned char* Ar = Ab + (size_t)rs * SLOT + (g == 0 ? 0u : PSOFF);
    unsigned char* Uw  = Ab + (size_t)wsl * SLOT;
    unsigned char* PSw = Uw + PSOFF;
    const long long* aP0 = (const long long*)Ar + aOff0;
    const long long* aP1 = (const long long*)Ar + aOff1;

    LOADA(A, 0) LOADA(B, 1) LOADA(C, 2) LOADA(D, 3)   // A half of the fill

    floatx4 acc00 = {0.f,0.f,0.f,0.f}, acc01 = {0.f,0.f,0.f,0.f};
    floatx4 acc02 = {0.f,0.f,0.f,0.f}, acc03 = {0.f,0.f,0.f,0.f};
    floatx4 acc10 = {0.f,0.f,0.f,0.f}, acc11 = {0.f,0.f,0.f,0.f};
    floatx4 acc12 = {0.f,0.f,0.f,0.f}, acc13 = {0.f,0.f,0.f,0.f};

    for (int kc = 0; kc < 12; kc += 4) {   // compute 0..11, load 4..15
      DOMFMA(A) LOADA(A, kc + 4) LOADB(A, kc + 4)
      DOMFMA(B) LOADA(B, kc + 5) LOADB(B, kc + 5)
      DOMFMA(C) LOADA(C, kc + 6) LOADB(C, kc + 6)
      DOMFMA(D) LOADA(D, kc + 7) LOADB(D, kc + 7)
    }
    // tail: consume kc 12..15 while prefetching NEXT STEP's B (kc 0..3)
    DOMFMA(A) LOADB(A, 0)
    DOMFMA(B) LOADB(B, 1)
    DOMFMA(C) LOADB(C, 2)
    DOMFMA(D) LOADB(D, 3)

    // publish partials: eb[wv][row 0..31][col 0..63]
#pragma unroll
    for (int r = 0; r < 4; ++r) {
      eb[wv][kq * 4 + r][lane15]      = acc00[r];
      eb[wv][kq * 4 + r][16 + lane15] = acc01[r];
      eb[wv][kq * 4 + r][32 + lane15] = acc02[r];
      eb[wv][kq * 4 + r][48 + lane15] = acc03[r];
      eb[wv][16 + kq * 4 + r][lane15]      = acc10[r];
      eb[wv][16 + kq * 4 + r][16 + lane15] = acc11[r];
      eb[wv][16 + kq * 4 + r][32 + lane15] = acc12[r];
      eb[wv][16 + kq * 4 + r][48 + lane15] = acc13[r];
    }
    __syncthreads();

    // ---- epilogue on register state ----
    f32x4 m1, m2;
    {
      const f32x4 p0 = *(const f32x4*)&eb[0][erow][c4];
      const f32x4 p1 = *(const f32x4*)&eb[1][erow][c4];
      const f32x4 p2 = *(const f32x4*)&eb[2][erow][c4];
      const f32x4 p3 = *(const f32x4*)&eb[3][erow][c4];
      const f32x4 q0 = *(const f32x4*)&eb[4][erow][c4];
      const f32x4 q1 = *(const f32x4*)&eb[5][erow][c4];
      const f32x4 q2 = *(const f32x4*)&eb[6][erow][c4];
      const f32x4 q3 = *(const f32x4*)&eb[7][erow][c4];
      m1 = ((p0 + p1) + (p2 + p3)) * ACC_INV;
      m2 = ((q0 + q1) + (q2 + q3)) * ACC_INV;
    }
    float uf[4], pf[4];
#pragma unroll
    for (int e = 0; e < 4; ++e) {
      const float xv = xcur[e], s = scur[e], p = pcur[e];
      const float phi = fmaxf(xv, 0.f), gg = fmaxf(s, 0.f), psi = fmaxf(p, 0.f);
      const float xn = xv + DT_C * (-xv + m1[e] + Wb4[e]) * fr4[e];
      const float sn = p + DT_C * (-s + wp4[e] * psi + phi);   // base is p (as in source)
      const float pn = p + DT_C * (-p + m2[e] + Tb4[e] + ws4[e] * gg);
      xcur[e] = xn; scur[e] = sn; pcur[e] = pn;
      uf[e] = ASCALE * fmaxf(xn, 0.f) * fmaxf(sn, 0.f);
      pf[e] = ASCALE * fmaxf(pn, 0.f);
    }
    if (t == NSTEPS - 1) {
      __builtin_nontemporal_store(xcur, (f32x4*)(xs + (size_t)t * BB * NN + eidx));
      __builtin_nontemporal_store(xcur, (f32x4*)(out + eidx));
    } else {
      sysstore((unsigned*)(Uw + fob), pack4_fp8(uf[0], uf[1], uf[2], uf[3]));
      sysstore((unsigned*)(PSw + fob), pack4_fp8(pf[0], pf[1], pf[2], pf[3]));
      asm volatile("s_waitcnt vmcnt(0)" ::: "memory");  // U,PS at L3; B prefetch retired
      __syncthreads();                                  // all waves' stores retired
      __builtin_nontemporal_store(xcur,                 // HBM write rides the spin
          (f32x4*)(xs + (size_t)t * BB * NN + eidx));
      if (tid == 0) {
        unsigned* leaf = bar + 32 * (1 + x);
        const unsigned v = __hip_atomic_fetch_add(leaf, 1u, __ATOMIC_RELAXED,
                                                  __HIP_MEMORY_SCOPE_AGENT);
        if (v + 1 == 32u * (unsigned)(t + 1))           // last arrival on this leaf
          __hip_atomic_fetch_add(bar, 1u, __ATOMIC_RELAXED, __HIP_MEMORY_SCOPE_AGENT);
        while (__hip_atomic_load(bar, __ATOMIC_RELAXED, __HIP_MEMORY_SCOPE_AGENT)
               < 8u * (unsigned)(t + 1))
          __builtin_amdgcn_s_sleep(1);
      }
      __syncthreads();
    }
  }
}

extern "C" void kernel_launch(void* const* d_in, const int* in_sizes, int n_in,
                              void* d_out, int out_size, void* d_ws, size_t ws_size,
                              hipStream_t stream) {
  const float* x0   = (const float*)d_in[0];
  const float* fri  = (const float*)d_in[1];
  const float* Ww   = (const float*)d_in[2];
  const float* Wb   = (const float*)d_in[3];
  const float* Tw   = (const float*)d_in[4];
  const float* Tb   = (const float*)d_in[5];
  const float* wp2s = (const float*)d_in[6];
  const float* ws2p = (const float*)d_in[7];
  float* out = (float*)d_out;

  const size_t BN = (size_t)BB * NN;
  const size_t NW = (size_t)NN * NN;

  const size_t needCached = 4096 + 64 * (size_t)SLOT + 2 * NW;  // ~75.5 MB
  const bool cached = ws_size >= needCached;
  const size_t nslots = cached ? 64 : 2;

  unsigned* bar = (unsigned*)d_ws;                       // 4 KB
  unsigned char* Abuf = (unsigned char*)d_ws + 4096;     // nslots x 1 MB
  unsigned char* Wf = Abuf + nslots * (size_t)SLOT;
  unsigned char* Tf = Wf + NW;

  hipMemsetAsync(bar, 0, 4096, stream);
  const int chalf = (int)(NW / 2048);
  convert_kernel<<<2 * chalf, 256, 0, stream>>>(Ww, Wf, Tw, Tf, chalf);
  init_kernel<<<(int)(BN / 256), 256, 0, stream>>>(x0, Abuf);

  void* kargs[] = {
    (void*)&Wf, (void*)&Tf, (void*)&Wb, (void*)&Tb, (void*)&wp2s, (void*)&ws2p,
    (void*)&fri, (void*)&x0, (void*)&Abuf, (void*)&out, (void*)&bar
  };
  if (cached) {
    hipLaunchCooperativeKernel((const void*)fused_kernel<true>, dim3(256),
                               dim3(512), kargs, 0, stream);
  } else {
    hipLaunchCooperativeKernel((const void*)fused_kernel<false>, dim3(256),
                               dim3(512), kargs, 0, stream);
  }
}